// Round 5
// baseline (90.057 us; speedup 1.0000x reference)
//
#include <hip/hip_runtime.h>
#include <math.h>

#define NB 2
#define NL 256
#define NH 768
#define NI 1536
#define NM (NB * NL)   // 512

typedef __attribute__((ext_vector_type(8))) short bf16x8;
typedef __attribute__((ext_vector_type(4))) float f32x4;

#if __has_builtin(__builtin_amdgcn_exp2f)
#define FAST_EXP2(x) __builtin_amdgcn_exp2f(x)
#else
#define FAST_EXP2(x) exp2f(x)
#endif
#if __has_builtin(__builtin_amdgcn_rcpf)
#define FAST_RCP(x) __builtin_amdgcn_rcpf(x)
#else
#define FAST_RCP(x) (1.0f / (x))
#endif

// fp32 -> bf16 round-to-nearest-even, packed pair
__device__ __forceinline__ unsigned short f2bf(float f) {
  unsigned int u = __builtin_bit_cast(unsigned int, f);
  u += 0x7FFFu + ((u >> 16) & 1u);
  return (unsigned short)(u >> 16);
}
__device__ __forceinline__ unsigned int pack2(float lo, float hi) {
  return (unsigned int)f2bf(lo) | ((unsigned int)f2bf(hi) << 16);
}

// ---------------------------------------------------------------------------
// Kernel 1: start/end logits. One block per row m, 256 threads.
// ---------------------------------------------------------------------------
__global__ __launch_bounds__(256) void logits_kernel(
    const float* __restrict__ hs,
    const float* __restrict__ sw, const float* __restrict__ sb,
    const float* __restrict__ ew, const float* __restrict__ eb,
    float* __restrict__ out) {
  int m = blockIdx.x;
  int tid = threadIdx.x;
  const float* row = hs + (size_t)m * NH;
  float accs = 0.f, acce = 0.f;
  for (int h = tid; h < NH; h += 256) {
    float v = row[h];
    accs = fmaf(v, sw[h], accs);
    acce = fmaf(v, ew[h], acce);
  }
  for (int off = 32; off > 0; off >>= 1) {
    accs += __shfl_down(accs, off, 64);
    acce += __shfl_down(acce, off, 64);
  }
  __shared__ float s_s[4], s_e[4];
  int wid = tid >> 6;
  if ((tid & 63) == 0) { s_s[wid] = accs; s_e[wid] = acce; }
  __syncthreads();
  if (tid == 0) {
    float ts = s_s[0] + s_s[1] + s_s[2] + s_s[3];
    float te = s_e[0] + s_e[1] + s_e[2] + s_e[3];
    out[m]      = ts + sb[0];
    out[NM + m] = te + eb[0];
  }
}

// ---------------------------------------------------------------------------
// Kernel 2: bf16 MFMA GEMM.  C(M x N) = hs(M x 768) @ W(768 x 1536)
// mode = blockIdx.z: 0 -> aOut[m][n] (+b1);  1 -> cT[b][i=n][t=m]
// Tile 64x96, BK=32, 4 waves (2m x 2n), grid (8,16,2) = 256 blocks.
// LDS rows of 64B = 4 x 16B slots, slot ^= (row&3) swizzle.
// ---------------------------------------------------------------------------
__global__ __launch_bounds__(256) void gemm_mfma(
    const float* __restrict__ hs, const float* __restrict__ w1,
    const float* __restrict__ b1, float* __restrict__ aOut,
    float* __restrict__ cT) {
  constexpr int BM = 64, BN = 96, BK = 32;
  __shared__ short A_lds[BM * BK];
  __shared__ short B_lds[BN * BK];

  const int mode = blockIdx.z;
  const float* __restrict__ W = w1 + (size_t)mode * NH * NI;
  const int m0 = blockIdx.x * BM;
  const int n0 = blockIdx.y * BN;
  const int tid = threadIdx.x;
  const int lane = tid & 63;
  const int wid = tid >> 6;
  const int wr = wid >> 1, wc = wid & 1;

  const int ar  = tid >> 2;
  const int akq = (tid & 3) * 8;
  const int bkq = (tid >> 5) * 4;
  const int bnl = tid & 31;

  f32x4 acc[2][3] = {};

  for (int k0 = 0; k0 < NH; k0 += BK) {
    const float* pa = hs + (size_t)(m0 + ar) * NH + k0 + akq;
    float4 a0 = *reinterpret_cast<const float4*>(pa);
    float4 a1 = *reinterpret_cast<const float4*>(pa + 4);
    float bv[4][3];
#pragma unroll
    for (int j = 0; j < 4; ++j) {
      const float* pb = W + (size_t)(k0 + bkq + j) * NI + n0 + bnl;
#pragma unroll
      for (int nn = 0; nn < 3; ++nn) bv[j][nn] = pb[nn * 32];
    }
    __syncthreads();
    {
      int4 v;
      v.x = (int)pack2(a0.x, a0.y);
      v.y = (int)pack2(a0.z, a0.w);
      v.z = (int)pack2(a1.x, a1.y);
      v.w = (int)pack2(a1.z, a1.w);
      const int off = ar * 64 + (((akq >> 3) ^ (ar & 3)) << 4);
      *reinterpret_cast<int4*>(reinterpret_cast<char*>(A_lds) + off) = v;
    }
#pragma unroll
    for (int nn = 0; nn < 3; ++nn) {
      const int n = bnl + nn * 32;
      uint2 v;
      v.x = pack2(bv[0][nn], bv[1][nn]);
      v.y = pack2(bv[2][nn], bv[3][nn]);
      const int off = n * 64 + (((bkq >> 3) ^ (n & 3)) << 4) + ((bkq & 4) << 1);
      *reinterpret_cast<uint2*>(reinterpret_cast<char*>(B_lds) + off) = v;
    }
    __syncthreads();
    const int lr = lane & 15, ls = lane >> 4;
    bf16x8 af[2], bf[3];
#pragma unroll
    for (int mt = 0; mt < 2; ++mt) {
      const int row = wr * 32 + mt * 16 + lr;
      const int off = row * 64 + ((ls ^ (row & 3)) << 4);
      af[mt] = *reinterpret_cast<const bf16x8*>(reinterpret_cast<const char*>(A_lds) + off);
    }
#pragma unroll
    for (int nt = 0; nt < 3; ++nt) {
      const int nrow = wc * 48 + nt * 16 + lr;
      const int off = nrow * 64 + ((ls ^ (nrow & 3)) << 4);
      bf[nt] = *reinterpret_cast<const bf16x8*>(reinterpret_cast<const char*>(B_lds) + off);
    }
#pragma unroll
    for (int mt = 0; mt < 2; ++mt)
#pragma unroll
      for (int nt = 0; nt < 3; ++nt)
        acc[mt][nt] = __builtin_amdgcn_mfma_f32_16x16x32_bf16(af[mt], bf[nt], acc[mt][nt], 0, 0, 0);
  }

  const int lr = lane & 15, lq = lane >> 4;
  if (mode == 0) {
#pragma unroll
    for (int nt = 0; nt < 3; ++nt) {
      const int n = n0 + wc * 48 + nt * 16 + lr;
      const float bias = b1[n];
#pragma unroll
      for (int mt = 0; mt < 2; ++mt) {
        const int mb = m0 + wr * 32 + mt * 16 + lq * 4;
#pragma unroll
        for (int r = 0; r < 4; ++r)
          aOut[(size_t)(mb + r) * NI + n] = acc[mt][nt][r] + bias;
      }
    }
  } else {
    const int b = m0 >> 8;
    const int tb = (m0 & (NL - 1)) + wr * 32;
#pragma unroll
    for (int nt = 0; nt < 3; ++nt) {
      const int i = n0 + wc * 48 + nt * 16 + lr;
      float* dst = cT + (size_t)b * NI * NL + (size_t)i * NL + tb;
#pragma unroll
      for (int mt = 0; mt < 2; ++mt)
        *reinterpret_cast<f32x4*>(dst + mt * 16 + lq * 4) = acc[mt][nt];
    }
  }
}

// ---------------------------------------------------------------------------
// Kernel 3: span logits, s-pair register-tiled.
// Block = (s-pair, t-half): grid 512, 512 threads, 2 blocks/CU.
// t4 = tid&31 -> 32 lanes x float4 = 128 t; q = tid>>5 -> 16 i-chunks of 96.
// Each cT float4 load feeds 8 gelu evals (4 t x 2 s).
// ---------------------------------------------------------------------------
__global__ __launch_bounds__(512, 4) void span_kernel(
    const float* __restrict__ aRow,   // [M][I], b1 folded
    const float* __restrict__ cT,     // [B][I][L]
    const float* __restrict__ w2,
    const float* __restrict__ b2,
    float* __restrict__ out) {
  const int blk = blockIdx.x;        // [0, 512)
  const int sg  = blk >> 1;          // s-pair index
  const int th  = (blk & 1) * 128;   // t-half offset
  const int s0  = sg * 2;            // bs row of first s
  const int b   = s0 >> 8;
  const int tid = threadIdx.x;
  const int t4  = tid & 31;
  const int q   = tid >> 5;          // 0..15

  __shared__ float4 aw[NI];          // (a0, a1, w2, 0) 24 KB
  __shared__ float4 red[2][16][32];  // 16 KB

  const float* a0p = aRow + (size_t)s0 * NI;
  const float* a1p = a0p + NI;
  for (int i = tid; i < NI; i += 512)
    aw[i] = make_float4(a0p[i], a1p[i], w2[i], 0.f);
  __syncthreads();

  const float* cbase = cT + (size_t)b * NI * NL + th + t4 * 4;
  f32x4 acc0 = {0.f, 0.f, 0.f, 0.f};
  f32x4 acc1 = {0.f, 0.f, 0.f, 0.f};
  const int i0 = q * 96;

#define GEL(S, A, CVC, K)                                          \
  {                                                                \
    float x = (A) + (CVC);                                         \
    float u = x * x;                                               \
    float zn = x * fmaf(u, -0.1029434f, -2.3022082f);              \
    float d = FAST_EXP2(zn) + 1.0f;                                \
    float xw = x * awv.z;                                          \
    acc##S[K] = fmaf(xw, FAST_RCP(d), acc##S[K]);                  \
  }

#pragma unroll 2
  for (int i = i0; i < i0 + 96; ++i) {
    float4 cv = *reinterpret_cast<const float4*>(cbase + (size_t)i * NL);
    float4 awv = aw[i];
    GEL(0, awv.x, cv.x, 0)
    GEL(0, awv.x, cv.y, 1)
    GEL(0, awv.x, cv.z, 2)
    GEL(0, awv.x, cv.w, 3)
    GEL(1, awv.y, cv.x, 0)
    GEL(1, awv.y, cv.y, 1)
    GEL(1, awv.y, cv.z, 2)
    GEL(1, awv.y, cv.w, 3)
  }
#undef GEL

  red[0][q][t4] = make_float4(acc0[0], acc0[1], acc0[2], acc0[3]);
  red[1][q][t4] = make_float4(acc1[0], acc1[1], acc1[2], acc1[3]);
  __syncthreads();
  if (tid < 64) {
    const int s = tid >> 5;
    const int tt = tid & 31;
    float4 sum = make_float4(0.f, 0.f, 0.f, 0.f);
#pragma unroll
    for (int qq = 0; qq < 16; ++qq) {
      float4 v = red[s][qq][tt];
      sum.x += v.x; sum.y += v.y; sum.z += v.z; sum.w += v.w;
    }
    const float bb = b2[0];
    float4 o;
    o.x = sum.x + bb; o.y = sum.y + bb; o.z = sum.z + bb; o.w = sum.w + bb;
    *reinterpret_cast<float4*>(out + 2 * NM + (size_t)(s0 + s) * NL + th + tt * 4) = o;
  }
}

// ---------------------------------------------------------------------------
extern "C" void kernel_launch(void* const* d_in, const int* in_sizes, int n_in,
                              void* d_out, int out_size, void* d_ws, size_t ws_size,
                              hipStream_t stream) {
  const float* hs = (const float*)d_in[0];
  const float* sw = (const float*)d_in[1];
  const float* sb = (const float*)d_in[2];
  const float* ew = (const float*)d_in[3];
  const float* eb = (const float*)d_in[4];
  const float* w1 = (const float*)d_in[5];
  const float* b1 = (const float*)d_in[6];
  const float* w2 = (const float*)d_in[7];
  const float* b2 = (const float*)d_in[8];
  float* out = (float*)d_out;

  float* a  = (float*)d_ws;                           // M*I floats = 3 MB
  float* cT = (float*)d_ws + (size_t)NM * NI;         // B*I*L floats = 3 MB

  logits_kernel<<<NM, 256, 0, stream>>>(hs, sw, sb, ew, eb, out);

  dim3 ggrid(NM / 64, NI / 96, 2);
  gemm_mfma<<<ggrid, 256, 0, stream>>>(hs, w1, b1, a, cT);

  span_kernel<<<512, 512, 0, stream>>>(a, cT, w2, b2, out);
}

// Round 6
// 88.644 us; speedup vs baseline: 1.0159x; 1.0159x over previous
//
#include <hip/hip_runtime.h>
#include <math.h>

#define NB 2
#define NL 256
#define NH 768
#define NI 1536
#define NM (NB * NL)   // 512

typedef __attribute__((ext_vector_type(8))) short bf16x8;
typedef __attribute__((ext_vector_type(4))) float f32x4;

#if __has_builtin(__builtin_amdgcn_exp2f)
#define FAST_EXP2(x) __builtin_amdgcn_exp2f(x)
#else
#define FAST_EXP2(x) exp2f(x)
#endif
#if __has_builtin(__builtin_amdgcn_rcpf)
#define FAST_RCP(x) __builtin_amdgcn_rcpf(x)
#else
#define FAST_RCP(x) (1.0f / (x))
#endif

// fp32 -> bf16 round-to-nearest-even, packed pair
__device__ __forceinline__ unsigned short f2bf(float f) {
  unsigned int u = __builtin_bit_cast(unsigned int, f);
  u += 0x7FFFu + ((u >> 16) & 1u);
  return (unsigned short)(u >> 16);
}
__device__ __forceinline__ unsigned int pack2(float lo, float hi) {
  return (unsigned int)f2bf(lo) | ((unsigned int)f2bf(hi) << 16);
}

// ---------------------------------------------------------------------------
// Kernel 1: start/end logits. One block per row m, 256 threads.
// ---------------------------------------------------------------------------
__global__ __launch_bounds__(256) void logits_kernel(
    const float* __restrict__ hs,
    const float* __restrict__ sw, const float* __restrict__ sb,
    const float* __restrict__ ew, const float* __restrict__ eb,
    float* __restrict__ out) {
  int m = blockIdx.x;
  int tid = threadIdx.x;
  const float* row = hs + (size_t)m * NH;
  float accs = 0.f, acce = 0.f;
  for (int h = tid; h < NH; h += 256) {
    float v = row[h];
    accs = fmaf(v, sw[h], accs);
    acce = fmaf(v, ew[h], acce);
  }
  for (int off = 32; off > 0; off >>= 1) {
    accs += __shfl_down(accs, off, 64);
    acce += __shfl_down(acce, off, 64);
  }
  __shared__ float s_s[4], s_e[4];
  int wid = tid >> 6;
  if ((tid & 63) == 0) { s_s[wid] = accs; s_e[wid] = acce; }
  __syncthreads();
  if (tid == 0) {
    float ts = s_s[0] + s_s[1] + s_s[2] + s_s[3];
    float te = s_e[0] + s_e[1] + s_e[2] + s_e[3];
    out[m]      = ts + sb[0];
    out[NM + m] = te + eb[0];
  }
}

// ---------------------------------------------------------------------------
// Kernel 2: bf16 MFMA GEMM (unchanged from R5 — known good).
// mode = blockIdx.z: 0 -> aOut[m][n] (+b1);  1 -> cT[b][i=n][t=m]
// Tile 64x96, BK=32, 4 waves, grid (8,16,2) = 256 blocks.
// ---------------------------------------------------------------------------
__global__ __launch_bounds__(256) void gemm_mfma(
    const float* __restrict__ hs, const float* __restrict__ w1,
    const float* __restrict__ b1, float* __restrict__ aOut,
    float* __restrict__ cT) {
  constexpr int BM = 64, BN = 96, BK = 32;
  __shared__ short A_lds[BM * BK];
  __shared__ short B_lds[BN * BK];

  const int mode = blockIdx.z;
  const float* __restrict__ W = w1 + (size_t)mode * NH * NI;
  const int m0 = blockIdx.x * BM;
  const int n0 = blockIdx.y * BN;
  const int tid = threadIdx.x;
  const int lane = tid & 63;
  const int wid = tid >> 6;
  const int wr = wid >> 1, wc = wid & 1;

  const int ar  = tid >> 2;
  const int akq = (tid & 3) * 8;
  const int bkq = (tid >> 5) * 4;
  const int bnl = tid & 31;

  f32x4 acc[2][3] = {};

  for (int k0 = 0; k0 < NH; k0 += BK) {
    const float* pa = hs + (size_t)(m0 + ar) * NH + k0 + akq;
    float4 a0 = *reinterpret_cast<const float4*>(pa);
    float4 a1 = *reinterpret_cast<const float4*>(pa + 4);
    float bv[4][3];
#pragma unroll
    for (int j = 0; j < 4; ++j) {
      const float* pb = W + (size_t)(k0 + bkq + j) * NI + n0 + bnl;
#pragma unroll
      for (int nn = 0; nn < 3; ++nn) bv[j][nn] = pb[nn * 32];
    }
    __syncthreads();
    {
      int4 v;
      v.x = (int)pack2(a0.x, a0.y);
      v.y = (int)pack2(a0.z, a0.w);
      v.z = (int)pack2(a1.x, a1.y);
      v.w = (int)pack2(a1.z, a1.w);
      const int off = ar * 64 + (((akq >> 3) ^ (ar & 3)) << 4);
      *reinterpret_cast<int4*>(reinterpret_cast<char*>(A_lds) + off) = v;
    }
#pragma unroll
    for (int nn = 0; nn < 3; ++nn) {
      const int n = bnl + nn * 32;
      uint2 v;
      v.x = pack2(bv[0][nn], bv[1][nn]);
      v.y = pack2(bv[2][nn], bv[3][nn]);
      const int off = n * 64 + (((bkq >> 3) ^ (n & 3)) << 4) + ((bkq & 4) << 1);
      *reinterpret_cast<uint2*>(reinterpret_cast<char*>(B_lds) + off) = v;
    }
    __syncthreads();
    const int lr = lane & 15, ls = lane >> 4;
    bf16x8 af[2], bf[3];
#pragma unroll
    for (int mt = 0; mt < 2; ++mt) {
      const int row = wr * 32 + mt * 16 + lr;
      const int off = row * 64 + ((ls ^ (row & 3)) << 4);
      af[mt] = *reinterpret_cast<const bf16x8*>(reinterpret_cast<const char*>(A_lds) + off);
    }
#pragma unroll
    for (int nt = 0; nt < 3; ++nt) {
      const int nrow = wc * 48 + nt * 16 + lr;
      const int off = nrow * 64 + ((ls ^ (nrow & 3)) << 4);
      bf[nt] = *reinterpret_cast<const bf16x8*>(reinterpret_cast<const char*>(B_lds) + off);
    }
#pragma unroll
    for (int mt = 0; mt < 2; ++mt)
#pragma unroll
      for (int nt = 0; nt < 3; ++nt)
        acc[mt][nt] = __builtin_amdgcn_mfma_f32_16x16x32_bf16(af[mt], bf[nt], acc[mt][nt], 0, 0, 0);
  }

  const int lr = lane & 15, lq = lane >> 4;
  if (mode == 0) {
#pragma unroll
    for (int nt = 0; nt < 3; ++nt) {
      const int n = n0 + wc * 48 + nt * 16 + lr;
      const float bias = b1[n];
#pragma unroll
      for (int mt = 0; mt < 2; ++mt) {
        const int mb = m0 + wr * 32 + mt * 16 + lq * 4;
#pragma unroll
        for (int r = 0; r < 4; ++r)
          aOut[(size_t)(mb + r) * NI + n] = acc[mt][nt][r] + bias;
      }
    }
  } else {
    const int b = m0 >> 8;
    const int tb = (m0 & (NL - 1)) + wr * 32;
#pragma unroll
    for (int nt = 0; nt < 3; ++nt) {
      const int i = n0 + wc * 48 + nt * 16 + lr;
      float* dst = cT + (size_t)b * NI * NL + (size_t)i * NL + tb;
#pragma unroll
      for (int mt = 0; mt < 2; ++mt)
        *reinterpret_cast<f32x4*>(dst + mt * 16 + lq * 4) = acc[mt][nt];
    }
  }
}

// ---------------------------------------------------------------------------
// Kernel 3: span logits, v4.
// Grid 1024 = (256 s-pairs) x (4 t-quarters), 256 threads, ~27 KB LDS
// -> 4 blocks/CU = 4 waves/SIMD.
// Thread: t4 = tid&15 (16 lanes x float4 = 64 t), q = tid>>4 (16 i-chunks
// of 96). Each cv float4 feeds 8 gelus (4 t x 2 s) -> 8 indep chains.
// aw LDS skewed by i/96 so the 4 broadcast groups per wave hit distinct
// banks. Wave shfl_xor reduction (16,32) then tiny LDS cross-wave combine.
// ---------------------------------------------------------------------------
__global__ __launch_bounds__(256, 4) void span_kernel(
    const float* __restrict__ aRow,   // [M][I], b1 folded
    const float* __restrict__ cT,     // [B][I][L]
    const float* __restrict__ w2,
    const float* __restrict__ b2,
    float* __restrict__ out) {
  const int blk = blockIdx.x;          // 0..1023
  const int sg  = blk >> 2;            // s-pair 0..255
  const int tq  = blk & 3;             // t-quarter
  const int s0  = sg * 2;
  const int b   = s0 >> 8;
  const int tbase = tq * 64;
  const int tid = threadIdx.x;
  const int t4  = tid & 15;
  const int q   = tid >> 4;            // 0..15
  const int lane = tid & 63;
  const int w    = tid >> 6;

  __shared__ float4 aw[NI + 16];       // (a0, a1, w2, 0), index skew i + i/96
  __shared__ float4 red[4][2][16];     // [wave][s][t4]

  const float* a0p = aRow + (size_t)s0 * NI;
  const float* a1p = a0p + NI;
  for (int i = tid; i < NI; i += 256)
    aw[i + i / 96] = make_float4(a0p[i], a1p[i], w2[i], 0.f);
  __syncthreads();

  const float* cb = cT + ((size_t)b * NI + q * 96) * NL + tbase + t4 * 4;
  const float4* awq = aw + q * 97;

  f32x4 acc0 = {0.f, 0.f, 0.f, 0.f};
  f32x4 acc1 = {0.f, 0.f, 0.f, 0.f};

// 4 gelus (one s, 4 t) with 4-wide batched reciprocal (validated R4)
#define SBODY(ACC, AV, WV)                                                   \
  {                                                                          \
    float x0 = (AV) + cvv.x, x1 = (AV) + cvv.y;                              \
    float x2 = (AV) + cvv.z, x3 = (AV) + cvv.w;                              \
    float d0 = FAST_EXP2(x0 * fmaf(x0 * x0, -0.1029434f, -2.3022082f)) + 1.f;\
    float d1 = FAST_EXP2(x1 * fmaf(x1 * x1, -0.1029434f, -2.3022082f)) + 1.f;\
    float d2 = FAST_EXP2(x2 * fmaf(x2 * x2, -0.1029434f, -2.3022082f)) + 1.f;\
    float d3 = FAST_EXP2(x3 * fmaf(x3 * x3, -0.1029434f, -2.3022082f)) + 1.f;\
    float m01 = d0 * d1, m23 = d2 * d3;                                      \
    float r = FAST_RCP(m01 * m23);                                           \
    float r01 = r * m23, r23 = r * m01;                                      \
    ACC[0] = fmaf(x0 * (WV), r01 * d1, ACC[0]);                              \
    ACC[1] = fmaf(x1 * (WV), r01 * d0, ACC[1]);                              \
    ACC[2] = fmaf(x2 * (WV), r23 * d3, ACC[2]);                              \
    ACC[3] = fmaf(x3 * (WV), r23 * d2, ACC[3]);                              \
  }

  for (int ii = 0; ii < 96; ii += 4) {
    float4 cv[4];
#pragma unroll
    for (int j = 0; j < 4; ++j)
      cv[j] = *reinterpret_cast<const float4*>(cb + (size_t)(ii + j) * NL);
#pragma unroll
    for (int j = 0; j < 4; ++j) {
      float4 cvv = cv[j];
      float4 awv = awq[ii + j];
      SBODY(acc0, awv.x, awv.z)
      SBODY(acc1, awv.y, awv.z)
    }
  }
#undef SBODY

  // wave-level reduce over the 4 q-groups in this wave (lanes ^16, ^32)
#pragma unroll
  for (int k = 0; k < 4; ++k) {
    acc0[k] += __shfl_xor(acc0[k], 16, 64);
    acc0[k] += __shfl_xor(acc0[k], 32, 64);
    acc1[k] += __shfl_xor(acc1[k], 16, 64);
    acc1[k] += __shfl_xor(acc1[k], 32, 64);
  }
  if (lane < 16) {
    red[w][0][lane] = make_float4(acc0[0], acc0[1], acc0[2], acc0[3]);
    red[w][1][lane] = make_float4(acc1[0], acc1[1], acc1[2], acc1[3]);
  }
  __syncthreads();
  if (tid < 32) {
    const int s = tid >> 4;
    const int tt = tid & 15;
    float4 v0 = red[0][s][tt];
    float4 v1 = red[1][s][tt];
    float4 v2 = red[2][s][tt];
    float4 v3 = red[3][s][tt];
    const float bb = b2[0];
    float4 o;
    o.x = (v0.x + v1.x) + (v2.x + v3.x) + bb;
    o.y = (v0.y + v1.y) + (v2.y + v3.y) + bb;
    o.z = (v0.z + v1.z) + (v2.z + v3.z) + bb;
    o.w = (v0.w + v1.w) + (v2.w + v3.w) + bb;
    *reinterpret_cast<float4*>(out + 2 * NM + (size_t)(s0 + s) * NL + tbase + tt * 4) = o;
  }
}

// ---------------------------------------------------------------------------
extern "C" void kernel_launch(void* const* d_in, const int* in_sizes, int n_in,
                              void* d_out, int out_size, void* d_ws, size_t ws_size,
                              hipStream_t stream) {
  const float* hs = (const float*)d_in[0];
  const float* sw = (const float*)d_in[1];
  const float* sb = (const float*)d_in[2];
  const float* ew = (const float*)d_in[3];
  const float* eb = (const float*)d_in[4];
  const float* w1 = (const float*)d_in[5];
  const float* b1 = (const float*)d_in[6];
  const float* w2 = (const float*)d_in[7];
  const float* b2 = (const float*)d_in[8];
  float* out = (float*)d_out;

  float* a  = (float*)d_ws;                           // M*I floats = 3 MB
  float* cT = (float*)d_ws + (size_t)NM * NI;         // B*I*L floats = 3 MB

  logits_kernel<<<NM, 256, 0, stream>>>(hs, sw, sb, ew, eb, out);

  dim3 ggrid(NM / 64, NI / 96, 2);
  gemm_mfma<<<ggrid, 256, 0, stream>>>(hs, w1, b1, a, cT);

  span_kernel<<<1024, 256, 0, stream>>>(a, cT, w2, b2, out);
}

// Round 7
// 85.725 us; speedup vs baseline: 1.0505x; 1.0341x over previous
//
#include <hip/hip_runtime.h>
#include <math.h>

#define NB 2
#define NL 256
#define NH 768
#define NI 1536
#define NM (NB * NL)   // 512

typedef __attribute__((ext_vector_type(8))) short bf16x8;
typedef __attribute__((ext_vector_type(4))) float f32x4;
typedef __attribute__((ext_vector_type(2))) float f32x2;

#if __has_builtin(__builtin_amdgcn_exp2f)
#define FAST_EXP2(x) __builtin_amdgcn_exp2f(x)
#else
#define FAST_EXP2(x) exp2f(x)
#endif
#if __has_builtin(__builtin_amdgcn_rcpf)
#define FAST_RCP(x) __builtin_amdgcn_rcpf(x)
#else
#define FAST_RCP(x) (1.0f / (x))
#endif

// packed fp32 (VOP3P) — hipcc does not auto-emit these; force via asm.
__device__ __forceinline__ f32x2 pk_add(f32x2 a, f32x2 b) {
  f32x2 d; asm("v_pk_add_f32 %0, %1, %2" : "=v"(d) : "v"(a), "v"(b)); return d;
}
__device__ __forceinline__ f32x2 pk_mul(f32x2 a, f32x2 b) {
  f32x2 d; asm("v_pk_mul_f32 %0, %1, %2" : "=v"(d) : "v"(a), "v"(b)); return d;
}
__device__ __forceinline__ f32x2 pk_fma(f32x2 a, f32x2 b, f32x2 c) {
  f32x2 d; asm("v_pk_fma_f32 %0, %1, %2, %3" : "=v"(d) : "v"(a), "v"(b), "v"(c)); return d;
}

// fp32 -> bf16 round-to-nearest-even, packed pair
__device__ __forceinline__ unsigned short f2bf(float f) {
  unsigned int u = __builtin_bit_cast(unsigned int, f);
  u += 0x7FFFu + ((u >> 16) & 1u);
  return (unsigned short)(u >> 16);
}
__device__ __forceinline__ unsigned int pack2(float lo, float hi) {
  return (unsigned int)f2bf(lo) | ((unsigned int)f2bf(hi) << 16);
}

// ---------------------------------------------------------------------------
// Kernel 1: start/end logits. One block per row m, 256 threads.
// ---------------------------------------------------------------------------
__global__ __launch_bounds__(256) void logits_kernel(
    const float* __restrict__ hs,
    const float* __restrict__ sw, const float* __restrict__ sb,
    const float* __restrict__ ew, const float* __restrict__ eb,
    float* __restrict__ out) {
  int m = blockIdx.x;
  int tid = threadIdx.x;
  const float* row = hs + (size_t)m * NH;
  float accs = 0.f, acce = 0.f;
  for (int h = tid; h < NH; h += 256) {
    float v = row[h];
    accs = fmaf(v, sw[h], accs);
    acce = fmaf(v, ew[h], acce);
  }
  for (int off = 32; off > 0; off >>= 1) {
    accs += __shfl_down(accs, off, 64);
    acce += __shfl_down(acce, off, 64);
  }
  __shared__ float s_s[4], s_e[4];
  int wid = tid >> 6;
  if ((tid & 63) == 0) { s_s[wid] = accs; s_e[wid] = acce; }
  __syncthreads();
  if (tid == 0) {
    float ts = s_s[0] + s_s[1] + s_s[2] + s_s[3];
    float te = s_e[0] + s_e[1] + s_e[2] + s_e[3];
    out[m]      = ts + sb[0];
    out[NM + m] = te + eb[0];
  }
}

// ---------------------------------------------------------------------------
// Kernel 2: bf16 MFMA GEMM (unchanged — known good).
// mode = blockIdx.z: 0 -> aOut[m][n] (+b1);  1 -> cT[b][i=n][t=m]
// ---------------------------------------------------------------------------
__global__ __launch_bounds__(256) void gemm_mfma(
    const float* __restrict__ hs, const float* __restrict__ w1,
    const float* __restrict__ b1, float* __restrict__ aOut,
    float* __restrict__ cT) {
  constexpr int BM = 64, BN = 96, BK = 32;
  __shared__ short A_lds[BM * BK];
  __shared__ short B_lds[BN * BK];

  const int mode = blockIdx.z;
  const float* __restrict__ W = w1 + (size_t)mode * NH * NI;
  const int m0 = blockIdx.x * BM;
  const int n0 = blockIdx.y * BN;
  const int tid = threadIdx.x;
  const int lane = tid & 63;
  const int wid = tid >> 6;
  const int wr = wid >> 1, wc = wid & 1;

  const int ar  = tid >> 2;
  const int akq = (tid & 3) * 8;
  const int bkq = (tid >> 5) * 4;
  const int bnl = tid & 31;

  f32x4 acc[2][3] = {};

  for (int k0 = 0; k0 < NH; k0 += BK) {
    const float* pa = hs + (size_t)(m0 + ar) * NH + k0 + akq;
    float4 a0 = *reinterpret_cast<const float4*>(pa);
    float4 a1 = *reinterpret_cast<const float4*>(pa + 4);
    float bv[4][3];
#pragma unroll
    for (int j = 0; j < 4; ++j) {
      const float* pb = W + (size_t)(k0 + bkq + j) * NI + n0 + bnl;
#pragma unroll
      for (int nn = 0; nn < 3; ++nn) bv[j][nn] = pb[nn * 32];
    }
    __syncthreads();
    {
      int4 v;
      v.x = (int)pack2(a0.x, a0.y);
      v.y = (int)pack2(a0.z, a0.w);
      v.z = (int)pack2(a1.x, a1.y);
      v.w = (int)pack2(a1.z, a1.w);
      const int off = ar * 64 + (((akq >> 3) ^ (ar & 3)) << 4);
      *reinterpret_cast<int4*>(reinterpret_cast<char*>(A_lds) + off) = v;
    }
#pragma unroll
    for (int nn = 0; nn < 3; ++nn) {
      const int n = bnl + nn * 32;
      uint2 v;
      v.x = pack2(bv[0][nn], bv[1][nn]);
      v.y = pack2(bv[2][nn], bv[3][nn]);
      const int off = n * 64 + (((bkq >> 3) ^ (n & 3)) << 4) + ((bkq & 4) << 1);
      *reinterpret_cast<uint2*>(reinterpret_cast<char*>(B_lds) + off) = v;
    }
    __syncthreads();
    const int lr = lane & 15, ls = lane >> 4;
    bf16x8 af[2], bf[3];
#pragma unroll
    for (int mt = 0; mt < 2; ++mt) {
      const int row = wr * 32 + mt * 16 + lr;
      const int off = row * 64 + ((ls ^ (row & 3)) << 4);
      af[mt] = *reinterpret_cast<const bf16x8*>(reinterpret_cast<const char*>(A_lds) + off);
    }
#pragma unroll
    for (int nt = 0; nt < 3; ++nt) {
      const int nrow = wc * 48 + nt * 16 + lr;
      const int off = nrow * 64 + ((ls ^ (nrow & 3)) << 4);
      bf[nt] = *reinterpret_cast<const bf16x8*>(reinterpret_cast<const char*>(B_lds) + off);
    }
#pragma unroll
    for (int mt = 0; mt < 2; ++mt)
#pragma unroll
      for (int nt = 0; nt < 3; ++nt)
        acc[mt][nt] = __builtin_amdgcn_mfma_f32_16x16x32_bf16(af[mt], bf[nt], acc[mt][nt], 0, 0, 0);
  }

  const int lr = lane & 15, lq = lane >> 4;
  if (mode == 0) {
#pragma unroll
    for (int nt = 0; nt < 3; ++nt) {
      const int n = n0 + wc * 48 + nt * 16 + lr;
      const float bias = b1[n];
#pragma unroll
      for (int mt = 0; mt < 2; ++mt) {
        const int mb = m0 + wr * 32 + mt * 16 + lq * 4;
#pragma unroll
        for (int r = 0; r < 4; ++r)
          aOut[(size_t)(mb + r) * NI + n] = acc[mt][nt][r] + bias;
      }
    }
  } else {
    const int b = m0 >> 8;
    const int tb = (m0 & (NL - 1)) + wr * 32;
#pragma unroll
    for (int nt = 0; nt < 3; ++nt) {
      const int i = n0 + wc * 48 + nt * 16 + lr;
      float* dst = cT + (size_t)b * NI * NL + (size_t)i * NL + tb;
#pragma unroll
      for (int mt = 0; mt < 2; ++mt)
        *reinterpret_cast<f32x4*>(dst + mt * 16 + lq * 4) = acc[mt][nt];
    }
  }
}

// ---------------------------------------------------------------------------
// Kernel 3: span logits v5 — packed-f32 gelu chain.
// Grid 1024 = (256 s-pairs) x (4 t-quarters), 256 threads.
// t4 = tid&15 (16 lanes x float4 = 64 t), q = tid>>4 (16 i-chunks of 96).
// All full-rate math as v_pk_* (2 elems/slot); exp2/rcp scalar; 4-wide
// batched rcp. LDS: a-pair as float2 + w2, both skewed by i/96.
// ---------------------------------------------------------------------------
__global__ __launch_bounds__(256, 4) void span_kernel(
    const float* __restrict__ aRow,   // [M][I], b1 folded
    const float* __restrict__ cT,     // [B][I][L]
    const float* __restrict__ w2,
    const float* __restrict__ b2,
    float* __restrict__ out) {
  const int blk = blockIdx.x;          // 0..1023
  const int sg  = blk >> 2;            // s-pair 0..255
  const int tq  = blk & 3;             // t-quarter
  const int s0  = sg * 2;
  const int b   = s0 >> 8;
  const int tbase = tq * 64;
  const int tid = threadIdx.x;
  const int t4  = tid & 15;
  const int q   = tid >> 4;            // 0..15
  const int lane = tid & 63;
  const int w    = tid >> 6;

  __shared__ float2 aw01[NI + 16];     // (a0, a1), skew i + i/96   ~12.1 KB
  __shared__ float  wls[NI + 16];      // w2, skewed                 ~6.1 KB
  __shared__ float4 red[4][2][16];     // 2 KB

  const float* a0p = aRow + (size_t)s0 * NI;
  const float* a1p = a0p + NI;
  for (int i = tid; i < NI; i += 256) {
    aw01[i + i / 96] = make_float2(a0p[i], a1p[i]);
    wls[i + i / 96]  = w2[i];
  }
  __syncthreads();

  const float* cb = cT + ((size_t)b * NI + q * 96) * NL + tbase + t4 * 4;
  const float2* awq = aw01 + q * 97;
  const float* wq = wls + q * 97;

  f32x2 acc0a = {0.f, 0.f}, acc0b = {0.f, 0.f};
  f32x2 acc1a = {0.f, 0.f}, acc1b = {0.f, 0.f};
  const f32x2 C1v = {-2.3022082f, -2.3022082f};   // -log2(e)*1.5957691
  const f32x2 C2v = {-0.1029434f, -0.1029434f};   // ... *0.044715
  const f32x2 ONE = {1.f, 1.f};

// 4 elems (4 t) for one s, fully packed full-rate chain + batched rcp
#define PKBODY(ACCA, ACCB, A)                                    \
  {                                                              \
    f32x2 av = {(A), (A)};                                       \
    f32x2 xa = pk_add(av, c01), xb = pk_add(av, c23);            \
    f32x2 ua = pk_mul(xa, xa), ub = pk_mul(xb, xb);              \
    f32x2 pa = pk_fma(ua, C2v, C1v), pb = pk_fma(ub, C2v, C1v);  \
    f32x2 za = pk_mul(xa, pa), zb = pk_mul(xb, pb);              \
    f32x2 ea = {FAST_EXP2(za.x), FAST_EXP2(za.y)};               \
    f32x2 eb = {FAST_EXP2(zb.x), FAST_EXP2(zb.y)};               \
    f32x2 da = pk_add(ea, ONE), db = pk_add(eb, ONE);            \
    float m01 = da.x * da.y, m23 = db.x * db.y;                  \
    float r = FAST_RCP(m01 * m23);                               \
    float r01 = r * m23, r23 = r * m01;                          \
    f32x2 sa = {r01 * da.y, r01 * da.x};                         \
    f32x2 sb2 = {r23 * db.y, r23 * db.x};                        \
    f32x2 xwa = pk_mul(xa, wv), xwb = pk_mul(xb, wv);            \
    ACCA = pk_fma(xwa, sa, ACCA);                                \
    ACCB = pk_fma(xwb, sb2, ACCB);                               \
  }

  for (int ii = 0; ii < 96; ii += 4) {
    float4 cv[4];
#pragma unroll
    for (int j = 0; j < 4; ++j)
      cv[j] = *reinterpret_cast<const float4*>(cb + (size_t)(ii + j) * NL);
#pragma unroll
    for (int j = 0; j < 4; ++j) {
      f32x2 c01 = {cv[j].x, cv[j].y};
      f32x2 c23 = {cv[j].z, cv[j].w};
      float2 awv = awq[ii + j];
      float wvs = wq[ii + j];
      f32x2 wv = {wvs, wvs};
      PKBODY(acc0a, acc0b, awv.x)
      PKBODY(acc1a, acc1b, awv.y)
    }
  }
#undef PKBODY

  f32x4 acc0 = {acc0a.x, acc0a.y, acc0b.x, acc0b.y};
  f32x4 acc1 = {acc1a.x, acc1a.y, acc1b.x, acc1b.y};

  // wave-level reduce over the 4 q-groups in this wave (lanes ^16, ^32)
#pragma unroll
  for (int k = 0; k < 4; ++k) {
    acc0[k] += __shfl_xor(acc0[k], 16, 64);
    acc0[k] += __shfl_xor(acc0[k], 32, 64);
    acc1[k] += __shfl_xor(acc1[k], 16, 64);
    acc1[k] += __shfl_xor(acc1[k], 32, 64);
  }
  if (lane < 16) {
    red[w][0][lane] = make_float4(acc0[0], acc0[1], acc0[2], acc0[3]);
    red[w][1][lane] = make_float4(acc1[0], acc1[1], acc1[2], acc1[3]);
  }
  __syncthreads();
  if (tid < 32) {
    const int s = tid >> 4;
    const int tt = tid & 15;
    float4 v0 = red[0][s][tt];
    float4 v1 = red[1][s][tt];
    float4 v2 = red[2][s][tt];
    float4 v3 = red[3][s][tt];
    const float bb = b2[0];
    float4 o;
    o.x = (v0.x + v1.x) + (v2.x + v3.x) + bb;
    o.y = (v0.y + v1.y) + (v2.y + v3.y) + bb;
    o.z = (v0.z + v1.z) + (v2.z + v3.z) + bb;
    o.w = (v0.w + v1.w) + (v2.w + v3.w) + bb;
    *reinterpret_cast<float4*>(out + 2 * NM + (size_t)(s0 + s) * NL + tbase + tt * 4) = o;
  }
}

// ---------------------------------------------------------------------------
extern "C" void kernel_launch(void* const* d_in, const int* in_sizes, int n_in,
                              void* d_out, int out_size, void* d_ws, size_t ws_size,
                              hipStream_t stream) {
  const float* hs = (const float*)d_in[0];
  const float* sw = (const float*)d_in[1];
  const float* sb = (const float*)d_in[2];
  const float* ew = (const float*)d_in[3];
  const float* eb = (const float*)d_in[4];
  const float* w1 = (const float*)d_in[5];
  const float* b1 = (const float*)d_in[6];
  const float* w2 = (const float*)d_in[7];
  const float* b2 = (const float*)d_in[8];
  float* out = (float*)d_out;

  float* a  = (float*)d_ws;                           // M*I floats = 3 MB
  float* cT = (float*)d_ws + (size_t)NM * NI;         // B*I*L floats = 3 MB

  logits_kernel<<<NM, 256, 0, stream>>>(hs, sw, sb, ew, eb, out);

  dim3 ggrid(NM / 64, NI / 96, 2);
  gemm_mfma<<<ggrid, 256, 0, stream>>>(hs, w1, b1, a, cT);

  span_kernel<<<1024, 256, 0, stream>>>(a, cT, w2, b2, out);
}